// Round 1
// baseline (292.209 us; speedup 1.0000x reference)
//
#include <hip/hip_runtime.h>
#include <hip/hip_bf16.h>

#define BB 32
#define SS 1600
#define DD 128
#define DFFN 2048
#define S2N 3200
#define RS 136  // LDS row stride in bf16 elems (128 + 8 pad -> conflict-free b128 reads)

typedef __attribute__((ext_vector_type(8))) short short8;
typedef __attribute__((ext_vector_type(4))) float floatx4;
typedef unsigned int u32;
typedef unsigned short u16;

__device__ __forceinline__ u32 encf(float f) {
  u32 u = __float_as_uint(f);
  return (u & 0x80000000u) ? ~u : (u | 0x80000000u);
}
__device__ __forceinline__ float decf(u32 e) {
  u32 u = (e & 0x80000000u) ? (e & 0x7fffffffu) : ~e;
  return __uint_as_float(u);
}
__device__ __forceinline__ u16 f2b(float x) {
  __hip_bfloat16 h = __float2bfloat16(x);
  return __builtin_bit_cast(u16, h);
}

// ---------------- K0: gate = sigmoid(score_embed); init m1u/m2u ----------------
__global__ __launch_bounds__(256) void k_gate_init(const float* __restrict__ se,
                                                   float* __restrict__ gate,
                                                   u32* __restrict__ m1u,
                                                   u32* __restrict__ m2u) {
  int i = blockIdx.x * 256 + threadIdx.x;  // 0 .. 639999
  if (i < (SS * SS / 4)) {
    float4 v = ((const float4*)se)[i];
    float4 g;
    g.x = 1.f / (1.f + __expf(-v.x));
    g.y = 1.f / (1.f + __expf(-v.y));
    g.z = 1.f / (1.f + __expf(-v.z));
    g.w = 1.f / (1.f + __expf(-v.w));
    ((float4*)gate)[i] = g;
  }
  if (i < BB * SS) {  // 0 encodes "below every finite float" in the monotonic map
    m1u[i] = 0u;
    m2u[i] = 0u;
  }
}

// ---------------- K1: q/k projection + l2norm (bf16 MFMA) ----------------
__global__ __launch_bounds__(256) void k_proj(const float* __restrict__ tgt,
                                              const float* __restrict__ memin,
                                              const float* __restrict__ w1,
                                              const float* __restrict__ b1,
                                              u16* __restrict__ qb, u16* __restrict__ kb) {
  __shared__ u16 sA[128 * RS];
  __shared__ u16 sB[128 * RS];
  __shared__ float sq[128];
  int tid = threadIdx.x;
  long row0 = (long)blockIdx.x * 128;
  const float* src;
  u16* dst;
  if (row0 < (long)BB * SS) { src = tgt + row0 * DD; dst = qb + row0 * DD; }
  else { src = memin + (row0 - (long)BB * SS) * DD; dst = kb + (row0 - (long)BB * SS) * DD; }

  // stage X tile (fp32 -> bf16) and w1 (fp32 -> bf16), both [128][128]
  for (int p = 0; p < 16; ++p) {
    int r = p * 8 + (tid >> 5);
    int c4 = (tid & 31) * 4;
    float4 v = *(const float4*)(src + r * DD + c4);
    u32 p0 = (u32)f2b(v.x) | ((u32)f2b(v.y) << 16);
    u32 p1 = (u32)f2b(v.z) | ((u32)f2b(v.w) << 16);
    *(u32*)&sA[r * RS + c4] = p0;
    *(u32*)&sA[r * RS + c4 + 2] = p1;
    float4 w = *(const float4*)(w1 + r * DD + c4);
    u32 q0 = (u32)f2b(w.x) | ((u32)f2b(w.y) << 16);
    u32 q1 = (u32)f2b(w.z) | ((u32)f2b(w.w) << 16);
    *(u32*)&sB[r * RS + c4] = q0;
    *(u32*)&sB[r * RS + c4 + 2] = q1;
  }
  if (tid < 128) sq[tid] = 0.f;
  __syncthreads();

  int lane = tid & 63, wv = tid >> 6;
  int wr = wv >> 1, wc = wv & 1;
  int l15 = lane & 15, lg = lane >> 4;

  floatx4 acc[4][4];
  for (int mi = 0; mi < 4; ++mi)
    for (int ni = 0; ni < 4; ++ni) acc[mi][ni] = (floatx4){0.f, 0.f, 0.f, 0.f};

  for (int kc = 0; kc < 4; ++kc) {
    int k0 = kc * 32 + lg * 8;
    short8 af[4], bfr[4];
    for (int mi = 0; mi < 4; ++mi) af[mi] = *(const short8*)&sA[(wr * 64 + mi * 16 + l15) * RS + k0];
    for (int ni = 0; ni < 4; ++ni) bfr[ni] = *(const short8*)&sB[(wc * 64 + ni * 16 + l15) * RS + k0];
    for (int mi = 0; mi < 4; ++mi)
      for (int ni = 0; ni < 4; ++ni)
        acc[mi][ni] = __builtin_amdgcn_mfma_f32_16x16x32_bf16(af[mi], bfr[ni], acc[mi][ni], 0, 0, 0);
  }

  float bvals[4];
  for (int ni = 0; ni < 4; ++ni) bvals[ni] = b1[wc * 64 + ni * 16 + l15];
  for (int mi = 0; mi < 4; ++mi)
    for (int r = 0; r < 4; ++r) {
      float s = 0.f;
      for (int ni = 0; ni < 4; ++ni) {
        float v = acc[mi][ni][r] + bvals[ni];
        acc[mi][ni][r] = v;
        s += v * v;
      }
      s += __shfl_xor(s, 1); s += __shfl_xor(s, 2);
      s += __shfl_xor(s, 4); s += __shfl_xor(s, 8);
      if (l15 == 0) atomicAdd(&sq[wr * 64 + mi * 16 + lg * 4 + r], s);
    }
  __syncthreads();

  // normalize, write bf16 into sA (safe: all MFMA reads done), then coalesced copy-out
  for (int mi = 0; mi < 4; ++mi)
    for (int r = 0; r < 4; ++r) {
      int row = wr * 64 + mi * 16 + lg * 4 + r;
      float scale = 1.f / fmaxf(sqrtf(sq[row]), 1e-12f);
      for (int ni = 0; ni < 4; ++ni)
        sA[row * RS + wc * 64 + ni * 16 + l15] = f2b(acc[mi][ni][r] * scale);
    }
  __syncthreads();
  for (int p = 0; p < 16; ++p) {
    int r = p * 8 + (tid >> 5);
    int c4 = (tid & 31) * 4;
    uint2 val = *(const uint2*)&sA[r * RS + c4];
    *(uint2*)(dst + r * DD + c4) = val;
  }
}

// ---------------- K2: attention QK^T * gate, row/col max ----------------
__global__ __launch_bounds__(256) void k_attn(const u16* __restrict__ qb,
                                              const u16* __restrict__ kb,
                                              const float* __restrict__ gate,
                                              u32* __restrict__ m1u, u32* __restrict__ m2u) {
  __shared__ u16 sQ[128 * RS];
  __shared__ u16 sK[128 * RS];
  __shared__ u32 cbuf[128];
  __shared__ u32 rbuf[128];
  int tid = threadIdx.x;
  int b = blockIdx.y;
  int s0 = blockIdx.x * 128;
  int lane = tid & 63, wv = tid >> 6;
  int wr = wv >> 1, wc = wv & 1;
  int l15 = lane & 15, lg = lane >> 4;
  const size_t base = (size_t)b * SS * DD;

  // stage Q tile once
  for (int p = 0; p < 8; ++p) {
    int r = p * 16 + (tid >> 4);
    int c8 = (tid & 15) * 8;
    int s = s0 + r;
    uint4 v = {0u, 0u, 0u, 0u};
    if (s < SS) v = *(const uint4*)(qb + base + (size_t)s * DD + c8);
    *(uint4*)&sQ[r * RS + c8] = v;
  }

  float rmax[4][4];
  for (int mi = 0; mi < 4; ++mi)
    for (int r = 0; r < 4; ++r) rmax[mi][r] = -1e30f;

  for (int tt = 0; tt < 13; ++tt) {
    int t0 = tt * 128;
    __syncthreads();  // prev iter's cbuf consumed & sK reads done
    for (int p = 0; p < 8; ++p) {
      int r = p * 16 + (tid >> 4);
      int c8 = (tid & 15) * 8;
      int t = t0 + r;
      uint4 v = {0u, 0u, 0u, 0u};
      if (t < SS) v = *(const uint4*)(kb + base + (size_t)t * DD + c8);
      *(uint4*)&sK[r * RS + c8] = v;
    }
    if (tid < 128) cbuf[tid] = 0u;
    __syncthreads();

    floatx4 acc[4][4];
    for (int mi = 0; mi < 4; ++mi)
      for (int ni = 0; ni < 4; ++ni) acc[mi][ni] = (floatx4){0.f, 0.f, 0.f, 0.f};
    for (int kc = 0; kc < 4; ++kc) {
      int k0 = kc * 32 + lg * 8;
      short8 af[4], bfr[4];
      for (int mi = 0; mi < 4; ++mi) af[mi] = *(const short8*)&sQ[(wr * 64 + mi * 16 + l15) * RS + k0];
      for (int ni = 0; ni < 4; ++ni) bfr[ni] = *(const short8*)&sK[(wc * 64 + ni * 16 + l15) * RS + k0];
      for (int mi = 0; mi < 4; ++mi)
        for (int ni = 0; ni < 4; ++ni)
          acc[mi][ni] = __builtin_amdgcn_mfma_f32_16x16x32_bf16(af[mi], bfr[ni], acc[mi][ni], 0, 0, 0);
    }

    float cmax[4];
    for (int ni = 0; ni < 4; ++ni) cmax[ni] = -1e30f;
    int tc0 = t0 + wc * 64 + l15;
    for (int mi = 0; mi < 4; ++mi)
      for (int r = 0; r < 4; ++r) {
        int srow = s0 + wr * 64 + mi * 16 + lg * 4 + r;
        bool sv = srow < SS;
        const float* grow = gate + (size_t)srow * SS;
        for (int ni = 0; ni < 4; ++ni) {
          int tcol = tc0 + ni * 16;
          float v = -1e30f;
          if (sv && tcol < SS) v = acc[mi][ni][r] * grow[tcol];
          rmax[mi][r] = fmaxf(rmax[mi][r], v);
          cmax[ni] = fmaxf(cmax[ni], v);
        }
      }
    for (int ni = 0; ni < 4; ++ni) {
      cmax[ni] = fmaxf(cmax[ni], __shfl_xor(cmax[ni], 16));
      cmax[ni] = fmaxf(cmax[ni], __shfl_xor(cmax[ni], 32));
    }
    if (lane < 16)
      for (int ni = 0; ni < 4; ++ni)
        atomicMax(&cbuf[wc * 64 + ni * 16 + lane], encf(cmax[ni]));
    __syncthreads();
    if (tid < 128) {
      int t = t0 + tid;
      if (t < SS) atomicMax(&m1u[b * SS + t], cbuf[tid]);
    }
  }

  // finalize row max (m2) — rows are block-exclusive, plain store
  __syncthreads();
  if (tid < 128) rbuf[tid] = 0u;
  __syncthreads();
  for (int mi = 0; mi < 4; ++mi)
    for (int r = 0; r < 4; ++r) {
      float v = rmax[mi][r];
      v = fmaxf(v, __shfl_xor(v, 1));
      v = fmaxf(v, __shfl_xor(v, 2));
      v = fmaxf(v, __shfl_xor(v, 4));
      v = fmaxf(v, __shfl_xor(v, 8));
      if (l15 == 0) atomicMax(&rbuf[wr * 64 + mi * 16 + lg * 4 + r], encf(v));
    }
  __syncthreads();
  if (tid < 128) {
    int s = s0 + tid;
    if (s < SS) m2u[b * SS + s] = rbuf[tid];
  }
}

// ---------------- K3a: x = BN1(concat(m1, m2)) ----------------
__global__ __launch_bounds__(256) void k_bn1(const u32* __restrict__ m1u,
                                             const u32* __restrict__ m2u,
                                             const float* __restrict__ g1,
                                             const float* __restrict__ be1,
                                             float* __restrict__ xb) {
  int i = blockIdx.x * 256 + threadIdx.x;
  if (i >= BB * S2N) return;
  int bb = i / S2N, c = i % S2N;
  u32 e = (c < SS) ? m1u[bb * SS + c] : m2u[bb * SS + (c - SS)];
  float v = decf(e);
  float gs = g1[c] * rsqrtf(1.f + 1e-5f);
  xb[i] = v * gs + be1[c];
}

// ---------------- K3b: hacc[cs][b][f] = partial(x @ w2^T) ----------------
// grid (64, 4): 32 f per block (4 waves x 8 f), c-split of 800 per blockIdx.y
__global__ __launch_bounds__(256) void k_gemm2(const float* __restrict__ xb,
                                               const float* __restrict__ w2,
                                               float* __restrict__ hacc) {
  int tid = threadIdx.x;
  int lane = tid & 63, wv = tid >> 6;
  int f0 = blockIdx.x * 32 + wv * 8;
  int cs = blockIdx.y;
  int cr0 = cs * 800;
  int c_sub = lane & 15, bq = lane >> 4;
  float acc[8][8];
  for (int a = 0; a < 8; ++a)
    for (int c = 0; c < 8; ++c) acc[a][c] = 0.f;
  const float4 z4 = {0.f, 0.f, 0.f, 0.f};
  for (int it = 0; it < 13; ++it) {
    int coff = it * 64 + c_sub * 4;
    bool ok = coff < 800;
    int c = cr0 + coff;
    float4 w4[8], x4[8];
    for (int jf = 0; jf < 8; ++jf)
      w4[jf] = ok ? *(const float4*)(w2 + (size_t)(f0 + jf) * S2N + c) : z4;
    for (int j = 0; j < 8; ++j)
      x4[j] = ok ? *(const float4*)(xb + (size_t)(bq * 8 + j) * S2N + c) : z4;
    for (int jf = 0; jf < 8; ++jf)
      for (int j = 0; j < 8; ++j) {
        float a = acc[jf][j];
        a = fmaf(w4[jf].x, x4[j].x, a);
        a = fmaf(w4[jf].y, x4[j].y, a);
        a = fmaf(w4[jf].z, x4[j].z, a);
        a = fmaf(w4[jf].w, x4[j].w, a);
        acc[jf][j] = a;
      }
  }
  for (int jf = 0; jf < 8; ++jf)
    for (int j = 0; j < 8; ++j) {
      float v = acc[jf][j];
      v += __shfl_xor(v, 1); v += __shfl_xor(v, 2);
      v += __shfl_xor(v, 4); v += __shfl_xor(v, 8);
      acc[jf][j] = v;
    }
  if ((lane & 15) == 0) {
    for (int jf = 0; jf < 8; ++jf)
      for (int j = 0; j < 8; ++j) {
        int b = bq * 8 + j;
        hacc[((size_t)cs * BB + b) * DFFN + f0 + jf] = acc[jf][j];
      }
  }
}

// ---------------- K3c: BN2 + relu + dot w3 + BN3 ----------------
__global__ __launch_bounds__(256) void k_final(const float* __restrict__ hacc,
                                               const float* __restrict__ b2,
                                               const float* __restrict__ g2,
                                               const float* __restrict__ be2,
                                               const float* __restrict__ w3,
                                               const float* __restrict__ b3,
                                               const float* __restrict__ g3,
                                               const float* __restrict__ be3,
                                               float* __restrict__ out) {
  __shared__ float wsum[4];
  int b = blockIdx.x;
  int tid = threadIdx.x;
  float bnc = rsqrtf(1.f + 1e-5f);
  float part = 0.f;
  for (int f = tid; f < DFFN; f += 256) {
    float s = hacc[((size_t)0 * BB + b) * DFFN + f] + hacc[((size_t)1 * BB + b) * DFFN + f] +
              hacc[((size_t)2 * BB + b) * DFFN + f] + hacc[((size_t)3 * BB + b) * DFFN + f];
    s += b2[f];
    s = s * (g2[f] * bnc) + be2[f];
    s = fmaxf(s, 0.f);
    part += s * w3[f];
  }
  for (int m = 1; m < 64; m <<= 1) part += __shfl_xor(part, m);
  if ((tid & 63) == 0) wsum[tid >> 6] = part;
  __syncthreads();
  if (tid == 0) {
    float tot = wsum[0] + wsum[1] + wsum[2] + wsum[3] + b3[0];
    out[b] = tot * (g3[0] * bnc) + be3[0];
  }
}

extern "C" void kernel_launch(void* const* d_in, const int* in_sizes, int n_in,
                              void* d_out, int out_size, void* d_ws, size_t ws_size,
                              hipStream_t stream) {
  const float* tgt = (const float*)d_in[0];
  const float* memin = (const float*)d_in[1];
  const float* se = (const float*)d_in[2];
  const float* w1 = (const float*)d_in[3];
  const float* b1 = (const float*)d_in[4];
  const float* g1 = (const float*)d_in[5];
  const float* be1 = (const float*)d_in[6];
  const float* w2 = (const float*)d_in[7];
  const float* b2 = (const float*)d_in[8];
  const float* g2 = (const float*)d_in[9];
  const float* be2 = (const float*)d_in[10];
  const float* w3 = (const float*)d_in[11];
  const float* b3 = (const float*)d_in[12];
  const float* g3 = (const float*)d_in[13];
  const float* be3 = (const float*)d_in[14];
  float* out = (float*)d_out;

  char* ws = (char*)d_ws;
  const size_t OFF_GATE = 0;
  const size_t OFF_QB = 10240000;
  const size_t OFF_KB = OFF_QB + 13107200;
  const size_t OFF_M1 = OFF_KB + 13107200;
  const size_t OFF_M2 = OFF_M1 + 204800;
  const size_t OFF_XB = OFF_M2 + 204800;
  const size_t OFF_HA = OFF_XB + 409600;
  const size_t NEEDED = OFF_HA + (size_t)4 * BB * DFFN * 4;
  if (ws_size < NEEDED) return;  // clean validation failure rather than OOB

  float* gate = (float*)(ws + OFF_GATE);
  u16* qb = (u16*)(ws + OFF_QB);
  u16* kb = (u16*)(ws + OFF_KB);
  u32* m1u = (u32*)(ws + OFF_M1);
  u32* m2u = (u32*)(ws + OFF_M2);
  float* xb = (float*)(ws + OFF_XB);
  float* hacc = (float*)(ws + OFF_HA);

  k_gate_init<<<2500, 256, 0, stream>>>(se, gate, m1u, m2u);
  k_proj<<<800, 256, 0, stream>>>(tgt, memin, w1, b1, qb, kb);
  k_attn<<<dim3(13, 32), 256, 0, stream>>>(qb, kb, gate, m1u, m2u);
  k_bn1<<<400, 256, 0, stream>>>(m1u, m2u, g1, be1, xb);
  k_gemm2<<<dim3(64, 4), 256, 0, stream>>>(xb, w2, hacc);
  k_final<<<32, 256, 0, stream>>>(hacc, b2, g2, be2, w3, b3, g3, be3, out);
}

// Round 2
// 167.495 us; speedup vs baseline: 1.7446x; 1.7446x over previous
//
#include <hip/hip_runtime.h>
#include <hip/hip_bf16.h>

#define BB 32
#define SS 1600
#define DD 128
#define DFFN 2048
#define S2N 3200
#define RS 136  // LDS row stride in bf16 elems (128 + 8 pad -> conflict-free b128 reads)

typedef __attribute__((ext_vector_type(8))) short short8;
typedef __attribute__((ext_vector_type(4))) float floatx4;
typedef unsigned int u32;
typedef unsigned short u16;

__device__ __forceinline__ u32 encf(float f) {
  u32 u = __float_as_uint(f);
  return (u & 0x80000000u) ? ~u : (u | 0x80000000u);
}
__device__ __forceinline__ float decf(u32 e) {
  u32 u = (e & 0x80000000u) ? (e & 0x7fffffffu) : ~e;
  return __uint_as_float(u);
}
__device__ __forceinline__ u16 f2b(float x) {
  __hip_bfloat16 h = __float2bfloat16(x);
  return __builtin_bit_cast(u16, h);
}

// ---------------- K0: gT[t][s] = sigmoid(se[s][t]) (64x64 LDS transpose); init m1u/m2u ----------------
__global__ __launch_bounds__(256) void k_init(const float* __restrict__ se,
                                              float* __restrict__ gT,
                                              u32* __restrict__ m1u,
                                              u32* __restrict__ m2u) {
  __shared__ float t64[64][65];
  int bx = blockIdx.x % 25, by = blockIdx.x / 25;
  int r0 = by * 64, c0 = bx * 64;
  int tr = threadIdx.x >> 4, tc4 = (threadIdx.x & 15) * 4;
  for (int p = 0; p < 4; ++p) {
    int r = p * 16 + tr;
    float4 v = *(const float4*)(se + (size_t)(r0 + r) * SS + c0 + tc4);
    t64[r][tc4 + 0] = 1.f / (1.f + __expf(-v.x));
    t64[r][tc4 + 1] = 1.f / (1.f + __expf(-v.y));
    t64[r][tc4 + 2] = 1.f / (1.f + __expf(-v.z));
    t64[r][tc4 + 3] = 1.f / (1.f + __expf(-v.w));
  }
  __syncthreads();
  for (int p = 0; p < 4; ++p) {
    int c = p * 16 + tr;  // output row = c0 + c
    float4 o;
    o.x = t64[tc4 + 0][c];
    o.y = t64[tc4 + 1][c];
    o.z = t64[tc4 + 2][c];
    o.w = t64[tc4 + 3][c];
    *(float4*)(gT + (size_t)(c0 + c) * SS + r0 + tc4) = o;
  }
  int i = blockIdx.x * 256 + threadIdx.x;
  if (i < BB * SS) {  // 0 encodes "below every finite float" in the monotonic map
    m1u[i] = 0u;
    m2u[i] = 0u;
  }
}

// ---------------- K1: q/k projection + l2norm (bf16 MFMA) ----------------
__global__ __launch_bounds__(256) void k_proj(const float* __restrict__ tgt,
                                              const float* __restrict__ memin,
                                              const float* __restrict__ w1,
                                              const float* __restrict__ b1,
                                              u16* __restrict__ qb, u16* __restrict__ kb) {
  __shared__ u16 sA[128 * RS];
  __shared__ u16 sB[128 * RS];
  __shared__ float sq[128];
  int tid = threadIdx.x;
  long row0 = (long)blockIdx.x * 128;
  const float* src;
  u16* dst;
  if (row0 < (long)BB * SS) { src = tgt + row0 * DD; dst = qb + row0 * DD; }
  else { src = memin + (row0 - (long)BB * SS) * DD; dst = kb + (row0 - (long)BB * SS) * DD; }

  for (int p = 0; p < 16; ++p) {
    int r = p * 8 + (tid >> 5);
    int c4 = (tid & 31) * 4;
    float4 v = *(const float4*)(src + r * DD + c4);
    u32 p0 = (u32)f2b(v.x) | ((u32)f2b(v.y) << 16);
    u32 p1 = (u32)f2b(v.z) | ((u32)f2b(v.w) << 16);
    *(u32*)&sA[r * RS + c4] = p0;
    *(u32*)&sA[r * RS + c4 + 2] = p1;
    float4 w = *(const float4*)(w1 + r * DD + c4);
    u32 q0 = (u32)f2b(w.x) | ((u32)f2b(w.y) << 16);
    u32 q1 = (u32)f2b(w.z) | ((u32)f2b(w.w) << 16);
    *(u32*)&sB[r * RS + c4] = q0;
    *(u32*)&sB[r * RS + c4 + 2] = q1;
  }
  if (tid < 128) sq[tid] = 0.f;
  __syncthreads();

  int lane = tid & 63, wv = tid >> 6;
  int wr = wv >> 1, wc = wv & 1;
  int l15 = lane & 15, lg = lane >> 4;

  floatx4 acc[4][4];
  for (int mi = 0; mi < 4; ++mi)
    for (int ni = 0; ni < 4; ++ni) acc[mi][ni] = (floatx4){0.f, 0.f, 0.f, 0.f};

  for (int kc = 0; kc < 4; ++kc) {
    int k0 = kc * 32 + lg * 8;
    short8 af[4], bfr[4];
    for (int mi = 0; mi < 4; ++mi) af[mi] = *(const short8*)&sA[(wr * 64 + mi * 16 + l15) * RS + k0];
    for (int ni = 0; ni < 4; ++ni) bfr[ni] = *(const short8*)&sB[(wc * 64 + ni * 16 + l15) * RS + k0];
    for (int mi = 0; mi < 4; ++mi)
      for (int ni = 0; ni < 4; ++ni)
        acc[mi][ni] = __builtin_amdgcn_mfma_f32_16x16x32_bf16(af[mi], bfr[ni], acc[mi][ni], 0, 0, 0);
  }

  float bvals[4];
  for (int ni = 0; ni < 4; ++ni) bvals[ni] = b1[wc * 64 + ni * 16 + l15];
  for (int mi = 0; mi < 4; ++mi)
    for (int r = 0; r < 4; ++r) {
      float s = 0.f;
      for (int ni = 0; ni < 4; ++ni) {
        float v = acc[mi][ni][r] + bvals[ni];
        acc[mi][ni][r] = v;
        s += v * v;
      }
      s += __shfl_xor(s, 1); s += __shfl_xor(s, 2);
      s += __shfl_xor(s, 4); s += __shfl_xor(s, 8);
      if (l15 == 0) atomicAdd(&sq[wr * 64 + mi * 16 + lg * 4 + r], s);
    }
  __syncthreads();

  for (int mi = 0; mi < 4; ++mi)
    for (int r = 0; r < 4; ++r) {
      int row = wr * 64 + mi * 16 + lg * 4 + r;
      float scale = 1.f / fmaxf(sqrtf(sq[row]), 1e-12f);
      for (int ni = 0; ni < 4; ++ni)
        sA[row * RS + wc * 64 + ni * 16 + l15] = f2b(acc[mi][ni][r] * scale);
    }
  __syncthreads();
  for (int p = 0; p < 16; ++p) {
    int r = p * 8 + (tid >> 5);
    int c4 = (tid & 31) * 4;
    uint2 val = *(const uint2*)&sA[r * RS + c4];
    *(uint2*)(dst + r * DD + c4) = val;
  }
}

// ---------------- K2: one 128x128 attn tile pair per block ----------------
__global__ __launch_bounds__(256) void k_attn(const u16* __restrict__ qb,
                                              const u16* __restrict__ kb,
                                              const float* __restrict__ gT,
                                              u32* __restrict__ m1u, u32* __restrict__ m2u) {
  __shared__ u16 sQ[128 * RS];
  __shared__ u16 sK[128 * RS];
  __shared__ float scmax[2][128];
  __shared__ float srmax[2][128];
  int tid = threadIdx.x;
  int b = blockIdx.z;
  // edge tiles clamp-overlap: max is idempotent, so recompute beats bounds checks
  int t0 = (blockIdx.x == 12) ? (SS - 128) : blockIdx.x * 128;
  int s0 = (blockIdx.y == 12) ? (SS - 128) : blockIdx.y * 128;
  int lane = tid & 63, wv = tid >> 6;
  int wr = wv >> 1, wc = wv & 1;
  int l15 = lane & 15, lg = lane >> 4;
  const size_t base = (size_t)b * SS * DD;

  {
    int r = tid >> 4;
    int c8 = (tid & 15) * 8;
    for (int p = 0; p < 8; ++p) {
      int rr = p * 16 + r;
      *(uint4*)&sQ[rr * RS + c8] = *(const uint4*)(qb + base + (size_t)(s0 + rr) * DD + c8);
      *(uint4*)&sK[rr * RS + c8] = *(const uint4*)(kb + base + (size_t)(t0 + rr) * DD + c8);
    }
  }

  // prefetch gate (transposed) early: per lane 16 aligned float4 loads, latency hides under MFMA
  floatx4 g4[4][4];
  {
    int srow0 = s0 + wr * 64 + lg * 4;
    int tc0 = t0 + wc * 64 + l15;
    for (int mi = 0; mi < 4; ++mi)
      for (int ni = 0; ni < 4; ++ni)
        g4[mi][ni] = *(const floatx4*)(gT + (size_t)(tc0 + ni * 16) * SS + srow0 + mi * 16);
  }
  __syncthreads();

  floatx4 acc[4][4];
  for (int mi = 0; mi < 4; ++mi)
    for (int ni = 0; ni < 4; ++ni) acc[mi][ni] = (floatx4){0.f, 0.f, 0.f, 0.f};
  for (int kc = 0; kc < 4; ++kc) {
    int k0 = kc * 32 + lg * 8;
    short8 af[4], bfr[4];
    for (int mi = 0; mi < 4; ++mi) af[mi] = *(const short8*)&sQ[(wr * 64 + mi * 16 + l15) * RS + k0];
    for (int ni = 0; ni < 4; ++ni) bfr[ni] = *(const short8*)&sK[(wc * 64 + ni * 16 + l15) * RS + k0];
    for (int mi = 0; mi < 4; ++mi)
      for (int ni = 0; ni < 4; ++ni)
        acc[mi][ni] = __builtin_amdgcn_mfma_f32_16x16x32_bf16(af[mi], bfr[ni], acc[mi][ni], 0, 0, 0);
  }

  // gate multiply + row/col max
  float rmax[4][4];
  for (int mi = 0; mi < 4; ++mi)
    for (int r = 0; r < 4; ++r) rmax[mi][r] = -1e30f;
  float cmax[4];
  for (int ni = 0; ni < 4; ++ni) cmax[ni] = -1e30f;

  for (int mi = 0; mi < 4; ++mi)
    for (int ni = 0; ni < 4; ++ni)
      for (int r = 0; r < 4; ++r) {
        float v = acc[mi][ni][r] * g4[mi][ni][r];
        rmax[mi][r] = fmaxf(rmax[mi][r], v);
        cmax[ni] = fmaxf(cmax[ni], v);
      }

  // column max: reduce over lg (rows) -> all lanes hold col max for col ni*16+l15
  for (int ni = 0; ni < 4; ++ni) {
    cmax[ni] = fmaxf(cmax[ni], __shfl_xor(cmax[ni], 16));
    cmax[ni] = fmaxf(cmax[ni], __shfl_xor(cmax[ni], 32));
  }
  if (lane < 16)
    for (int ni = 0; ni < 4; ++ni) scmax[wr][wc * 64 + ni * 16 + l15] = cmax[ni];

  // row max: reduce over l15 (cols)
  for (int mi = 0; mi < 4; ++mi)
    for (int r = 0; r < 4; ++r) {
      float v = rmax[mi][r];
      v = fmaxf(v, __shfl_xor(v, 1));
      v = fmaxf(v, __shfl_xor(v, 2));
      v = fmaxf(v, __shfl_xor(v, 4));
      v = fmaxf(v, __shfl_xor(v, 8));
      if (l15 == 0) srmax[wc][wr * 64 + mi * 16 + lg * 4 + r] = v;
    }
  __syncthreads();

  if (tid < 128) {
    float v = fmaxf(scmax[0][tid], scmax[1][tid]);
    atomicMax(&m1u[b * SS + t0 + tid], encf(v));
  } else {
    int i = tid - 128;
    float v = fmaxf(srmax[0][i], srmax[1][i]);
    atomicMax(&m2u[b * SS + s0 + i], encf(v));
  }
}

// ---------------- K3a: x = BN1(concat(m1, m2)) ----------------
__global__ __launch_bounds__(256) void k_bn1(const u32* __restrict__ m1u,
                                             const u32* __restrict__ m2u,
                                             const float* __restrict__ g1,
                                             const float* __restrict__ be1,
                                             float* __restrict__ xb) {
  int i = blockIdx.x * 256 + threadIdx.x;
  if (i >= BB * S2N) return;
  int bb = i / S2N, c = i % S2N;
  u32 e = (c < SS) ? m1u[bb * SS + c] : m2u[bb * SS + (c - SS)];
  float v = decf(e);
  float gs = g1[c] * rsqrtf(1.f + 1e-5f);
  xb[i] = v * gs + be1[c];
}

// ---------------- K3b: hacc[cs][b][f] = partial(x @ w2^T) ----------------
__global__ __launch_bounds__(256) void k_gemm2(const float* __restrict__ xb,
                                               const float* __restrict__ w2,
                                               float* __restrict__ hacc) {
  int tid = threadIdx.x;
  int lane = tid & 63, wv = tid >> 6;
  int f0 = blockIdx.x * 32 + wv * 8;
  int cs = blockIdx.y;
  int cr0 = cs * 800;
  int c_sub = lane & 15, bq = lane >> 4;
  float acc[8][8];
  for (int a = 0; a < 8; ++a)
    for (int c = 0; c < 8; ++c) acc[a][c] = 0.f;
  const float4 z4 = {0.f, 0.f, 0.f, 0.f};
  for (int it = 0; it < 13; ++it) {
    int coff = it * 64 + c_sub * 4;
    bool ok = coff < 800;
    int c = cr0 + coff;
    float4 w4[8], x4[8];
    for (int jf = 0; jf < 8; ++jf)
      w4[jf] = ok ? *(const float4*)(w2 + (size_t)(f0 + jf) * S2N + c) : z4;
    for (int j = 0; j < 8; ++j)
      x4[j] = ok ? *(const float4*)(xb + (size_t)(bq * 8 + j) * S2N + c) : z4;
    for (int jf = 0; jf < 8; ++jf)
      for (int j = 0; j < 8; ++j) {
        float a = acc[jf][j];
        a = fmaf(w4[jf].x, x4[j].x, a);
        a = fmaf(w4[jf].y, x4[j].y, a);
        a = fmaf(w4[jf].z, x4[j].z, a);
        a = fmaf(w4[jf].w, x4[j].w, a);
        acc[jf][j] = a;
      }
  }
  for (int jf = 0; jf < 8; ++jf)
    for (int j = 0; j < 8; ++j) {
      float v = acc[jf][j];
      v += __shfl_xor(v, 1); v += __shfl_xor(v, 2);
      v += __shfl_xor(v, 4); v += __shfl_xor(v, 8);
      acc[jf][j] = v;
    }
  if ((lane & 15) == 0) {
    for (int jf = 0; jf < 8; ++jf)
      for (int j = 0; j < 8; ++j) {
        int b = bq * 8 + j;
        hacc[((size_t)cs * BB + b) * DFFN + f0 + jf] = acc[jf][j];
      }
  }
}

// ---------------- K3c: BN2 + relu + dot w3 + BN3 ----------------
__global__ __launch_bounds__(256) void k_final(const float* __restrict__ hacc,
                                               const float* __restrict__ b2,
                                               const float* __restrict__ g2,
                                               const float* __restrict__ be2,
                                               const float* __restrict__ w3,
                                               const float* __restrict__ b3,
                                               const float* __restrict__ g3,
                                               const float* __restrict__ be3,
                                               float* __restrict__ out) {
  __shared__ float wsum[4];
  int b = blockIdx.x;
  int tid = threadIdx.x;
  float bnc = rsqrtf(1.f + 1e-5f);
  float part = 0.f;
  for (int f = tid; f < DFFN; f += 256) {
    float s = hacc[((size_t)0 * BB + b) * DFFN + f] + hacc[((size_t)1 * BB + b) * DFFN + f] +
              hacc[((size_t)2 * BB + b) * DFFN + f] + hacc[((size_t)3 * BB + b) * DFFN + f];
    s += b2[f];
    s = s * (g2[f] * bnc) + be2[f];
    s = fmaxf(s, 0.f);
    part += s * w3[f];
  }
  for (int m = 1; m < 64; m <<= 1) part += __shfl_xor(part, m);
  if ((tid & 63) == 0) wsum[tid >> 6] = part;
  __syncthreads();
  if (tid == 0) {
    float tot = wsum[0] + wsum[1] + wsum[2] + wsum[3] + b3[0];
    out[b] = tot * (g3[0] * bnc) + be3[0];
  }
}

extern "C" void kernel_launch(void* const* d_in, const int* in_sizes, int n_in,
                              void* d_out, int out_size, void* d_ws, size_t ws_size,
                              hipStream_t stream) {
  const float* tgt = (const float*)d_in[0];
  const float* memin = (const float*)d_in[1];
  const float* se = (const float*)d_in[2];
  const float* w1 = (const float*)d_in[3];
  const float* b1 = (const float*)d_in[4];
  const float* g1 = (const float*)d_in[5];
  const float* be1 = (const float*)d_in[6];
  const float* w2 = (const float*)d_in[7];
  const float* b2 = (const float*)d_in[8];
  const float* g2 = (const float*)d_in[9];
  const float* be2 = (const float*)d_in[10];
  const float* w3 = (const float*)d_in[11];
  const float* b3 = (const float*)d_in[12];
  const float* g3 = (const float*)d_in[13];
  const float* be3 = (const float*)d_in[14];
  float* out = (float*)d_out;

  char* ws = (char*)d_ws;
  const size_t OFF_GT = 0;
  const size_t OFF_QB = 10240000;
  const size_t OFF_KB = OFF_QB + 13107200;
  const size_t OFF_M1 = OFF_KB + 13107200;
  const size_t OFF_M2 = OFF_M1 + 204800;
  const size_t OFF_XB = OFF_M2 + 204800;
  const size_t OFF_HA = OFF_XB + 409600;
  const size_t NEEDED = OFF_HA + (size_t)4 * BB * DFFN * 4;
  if (ws_size < NEEDED) return;  // clean validation failure rather than OOB

  float* gT = (float*)(ws + OFF_GT);
  u16* qb = (u16*)(ws + OFF_QB);
  u16* kb = (u16*)(ws + OFF_KB);
  u32* m1u = (u32*)(ws + OFF_M1);
  u32* m2u = (u32*)(ws + OFF_M2);
  float* xb = (float*)(ws + OFF_XB);
  float* hacc = (float*)(ws + OFF_HA);

  k_init<<<625, 256, 0, stream>>>(se, gT, m1u, m2u);
  k_proj<<<800, 256, 0, stream>>>(tgt, memin, w1, b1, qb, kb);
  k_attn<<<dim3(13, 13, 32), 256, 0, stream>>>(qb, kb, gT, m1u, m2u);
  k_bn1<<<400, 256, 0, stream>>>(m1u, m2u, g1, be1, xb);
  k_gemm2<<<dim3(64, 4), 256, 0, stream>>>(xb, w2, hacc);
  k_final<<<32, 256, 0, stream>>>(hacc, b2, g2, be2, w3, b3, g3, be3, out);
}